// Round 1
// baseline (83.484 us; speedup 1.0000x reference)
//
#include <hip/hip_runtime.h>

// VQ-VAE codebook forward, B=8,C=64,H=64,W=64, K=8192, D=64.
// Reference quirk: the cross term is a SCALAR, so argmin over k is independent
// of n: idx[n] == argmin_k |book_k|^2 for all n.
// Outputs (concatenated float32):
//   [0 .. 2097151]      z_q permuted to [B,W,C,H]: out[b,w,c,h] = e[w], e=book[kmin]
//   [2097152..2129919]  idx: 32768 x float(kmin)
//   [2129920]           loss = 1.25 * mean((e[w] - in[b,c,h,w])^2)
//
// R4: fuse k3 into k2 via last-block-done (integer counter in ws, re-armed by
// k1 each iteration since ws is re-poisoned). Final 512-partial sum replicates
// k3's exact summation order -> loss bit-identical. Partials cross XCDs, so
// they move via agent-scope atomic load/store + __threadfence around the
// counter. Also: k2 issues its 4 input float4 loads BEFORE the kmin resolve so
// HBM latency overlaps the key reduction.
// Note: ~43 us of dur_us is the harness's 256 MB d_ws re-poison fill
// (6.2 TB/s in the profile) -- outside our control.

#define NTOT    2097152   // 8*64*64*64
#define NIDX    32768
#define K_ROWS  8192
#define K1_BLK  512       // 16 rows/block, 16 lanes (one float4) per row
#define K2_BLK  512
#define K2_ITER 4         // 524288 float4 tasks / (512*256)

// ws layout: [0 .. 4095]    512 x u64 per-block argmin keys
//            [4096 .. 6143] 512 x float loss partials
//            [6144 .. 6147] u32 arrival counter (zeroed by k1 each launch)

__global__ __launch_bounds__(256) void k1_argmin(const float* __restrict__ book,
                                                 unsigned long long* __restrict__ ws_keys,
                                                 unsigned int* __restrict__ ws_counter) {
    const int t   = threadIdx.x;
    const int rIn = t >> 4;                       // row within block, 0..15
    const int c4  = t & 15;                       // float4 column
    const int row = blockIdx.x * 16 + rIn;

    // re-arm the last-block counter (ws is poisoned before every iteration;
    // k1 fully completes before k2 starts, so no race)
    if (blockIdx.x == 0 && t == 0) *ws_counter = 0u;

    const float4 v = ((const float4*)book)[row * 16 + c4];   // fully coalesced
    float s = v.x * v.x + v.y * v.y + v.z * v.z + v.w * v.w;
    // reduce across the 16 contiguous lanes of this row
    s += __shfl_down(s, 8, 16);
    s += __shfl_down(s, 4, 16);
    s += __shfl_down(s, 2, 16);
    s += __shfl_down(s, 1, 16);

    __shared__ unsigned long long keys[16];
    if (c4 == 0) {
        // positive-float bits are monotone as uint -> u64 min gives min norm,
        // ties broken to LOWEST row (jnp.argmin semantics).
        keys[rIn] = ((unsigned long long)__float_as_uint(s) << 32)
                  | (unsigned int)row;
    }
    __syncthreads();
    if (t == 0) {
        unsigned long long k = keys[0];
        #pragma unroll
        for (int i = 1; i < 16; ++i) k = keys[i] < k ? keys[i] : k;
        ws_keys[blockIdx.x] = k;                  // plain store, no atomic
    }
}

__global__ __launch_bounds__(256) void k2_main(const float* __restrict__ in,
                                               const float* __restrict__ book,
                                               float* __restrict__ out,
                                               const unsigned long long* __restrict__ ws_keys,
                                               float* __restrict__ ws_part,
                                               unsigned int* __restrict__ ws_counter) {
    const int lane = threadIdx.x & 63, wid = threadIdx.x >> 6;
    const int tid  = blockIdx.x * 256 + threadIdx.x;   // 131072 threads

    // ---- prefetch the 4 input float4s NOW: addresses are kmin-independent,
    //      so their HBM latency overlaps wave0's key resolve below ----
    float4 z[K2_ITER];
    #pragma unroll
    for (int it = 0; it < K2_ITER; ++it)
        z[it] = ((const float4*)in)[tid + it * (K2_BLK * 256)];

    // ---- resolve kmin: wave 0 reduces the 512 L2-hot keys, LDS-broadcast ----
    __shared__ unsigned long long skey;
    if (wid == 0) {
        unsigned long long key = ~0ULL;
        #pragma unroll
        for (int j = 0; j < K1_BLK / 64; ++j) {   // 8 strided loads per lane
            unsigned long long o = ws_keys[lane + j * 64];
            key = o < key ? o : key;
        }
        #pragma unroll
        for (int off = 32; off > 0; off >>= 1) {
            unsigned long long o = __shfl_down(key, off, 64);
            key = o < key ? o : key;
        }
        if (lane == 0) skey = key;
    }
    __syncthreads();
    const int kmin = (int)(skey & 0xFFFFFFFFu);
    const float* __restrict__ e = book + kmin * 64;   // L2-hot broadcast

    // ---- idx output: 32768 floats == float(kmin) (blocks 0..31) ----
    if (tid < NIDX / 4) {
        const float kf = (float)kmin;
        ((float4*)(out + NTOT))[tid] = make_float4(kf, kf, kf, kf);
    }

    // ---- z_q out [B,W,C,H] + fused loss over in [B,C,H,W], 4 float4/thread ----
    float part = 0.f;
    #pragma unroll
    for (int it = 0; it < K2_ITER; ++it) {
        const int i = tid + it * (K2_BLK * 256);       // float4 index
        // z_q: float offset o=4i -> value e[(o>>12)&63]
        const float ev = e[(i >> 10) & 63];
        ((float4*)out)[i] = make_float4(ev, ev, ev, ev);
        // loss: in float4 i covers w = (4i&63)..+3
        const float4 zz = z[it];
        const float4 ef = ((const float4*)e)[i & 15];
        const float d0 = zz.x - ef.x, d1 = zz.y - ef.y;
        const float d2 = zz.z - ef.z, d3 = zz.w - ef.w;
        part += d0 * d0 + d1 * d1 + d2 * d2 + d3 * d3;
    }
    #pragma unroll
    for (int off = 32; off > 0; off >>= 1) part += __shfl_down(part, off, 64);

    __shared__ float sp[4];
    __shared__ int   sLast;
    if (lane == 0) sp[wid] = part;
    __syncthreads();
    if (threadIdx.x == 0) {
        const float blkSum = sp[0] + sp[1] + sp[2] + sp[3];
        // agent-scope store: bypasses the non-coherent per-XCD path so the
        // last block (possibly another XCD) sees it
        __hip_atomic_store(&ws_part[blockIdx.x], blkSum,
                           __ATOMIC_RELAXED, __HIP_MEMORY_SCOPE_AGENT);
        __threadfence();                               // partial visible before arrival
        const unsigned int v = atomicAdd(ws_counter, 1u);  // int atomic: deterministic
        sLast = (v == (unsigned int)(K2_BLK - 1));
    }
    __syncthreads();

    // ---- last block: fold 512 partials (exact k3 summation order) ----
    if (sLast && wid == 0) {
        __threadfence();                               // acquire side
        float s = 0.f;
        #pragma unroll
        for (int j = 0; j < K2_BLK / 64; ++j)
            s += __hip_atomic_load(&ws_part[lane + j * 64],
                                   __ATOMIC_RELAXED, __HIP_MEMORY_SCOPE_AGENT);
        #pragma unroll
        for (int off = 32; off > 0; off >>= 1) s += __shfl_down(s, off, 64);
        if (lane == 0)
            out[NTOT + NIDX] = s * (1.25f / (float)NTOT);
    }
}

extern "C" void kernel_launch(void* const* d_in, const int* in_sizes, int n_in,
                              void* d_out, int out_size, void* d_ws, size_t ws_size,
                              hipStream_t stream) {
    const float* in   = (const float*)d_in[0];   // [8,64,64,64] fp32
    const float* book = (const float*)d_in[1];   // [8192,64] fp32
    float* out = (float*)d_out;

    unsigned long long* ws_keys    = (unsigned long long*)d_ws;
    float*              ws_part    = (float*)((char*)d_ws + 4096);
    unsigned int*       ws_counter = (unsigned int*)((char*)d_ws + 6144);

    k1_argmin<<<K1_BLK, 256, 0, stream>>>(book, ws_keys, ws_counter);
    k2_main<<<K2_BLK, 256, 0, stream>>>(in, book, out, ws_keys, ws_part, ws_counter);
}

// Round 2
// 73.109 us; speedup vs baseline: 1.1419x; 1.1419x over previous
//
#include <hip/hip_runtime.h>

// VQ-VAE codebook forward, B=8,C=64,H=64,W=64, K=8192, D=64.
// Reference quirk: the cross term is a SCALAR, so argmin over k is independent
// of n: idx[n] == argmin_k |book_k|^2 for all n.
// Outputs (concatenated float32):
//   [0 .. 2097151]      z_q permuted to [B,W,C,H]: out[b,w,c,h] = e[w], e=book[kmin]
//   [2097152..2129919]  idx: 32768 x float(kmin)
//   [2129920]           loss = 1.25 * mean((e[w] - in[b,c,h,w])^2)
//
// R5: R4's k3-fusion kept, but the cross-XCD handoff no longer uses
// __threadfence(). Post-mortem of R4 (+16 us): a device-scope fence on gfx950
// compiles to an L2 writeback/invalidate (per-XCD L2s are non-coherent), and
// 512 blocks each flushed L2 while ~8 MB of z_q stores sat dirty -> massive
// serialization. Replacement: relaxed AGENT-scope atomic stores (emit
// global_store sc1 = write-through to the LLC, no dirty-L2 interaction) +
// s_waitcnt vmcnt(0) before the arrival atomicAdd. Reader side uses
// AGENT-scope sc1 loads (LLC). One coherence point, zero cache flushes.
// Loss summation order is bit-identical to the verified R3 k3 order.
// Note: ~43 us of dur_us is the harness's 256 MB d_ws re-poison fill
// (6.2-6.5 TB/s in the profile) -- outside our control.

#define NTOT    2097152   // 8*64*64*64
#define NIDX    32768
#define K_ROWS  8192
#define K1_BLK  512       // 16 rows/block, 16 lanes (one float4) per row
#define K2_BLK  512
#define K2_ITER 4         // 524288 float4 tasks / (512*256)

// ws layout: [0 .. 4095]    512 x u64 per-block argmin keys
//            [4096 .. 6143] 512 x float loss partials
//            [6144 .. 6147] u32 arrival counter (zeroed by k1 each launch)

__global__ __launch_bounds__(256) void k1_argmin(const float* __restrict__ book,
                                                 unsigned long long* __restrict__ ws_keys,
                                                 unsigned int* __restrict__ ws_counter) {
    const int t   = threadIdx.x;
    const int rIn = t >> 4;                       // row within block, 0..15
    const int c4  = t & 15;                       // float4 column
    const int row = blockIdx.x * 16 + rIn;

    // re-arm the last-block counter (ws is poisoned before every iteration;
    // k1 fully completes before k2 starts + end-of-kernel L2 writeback, so
    // k2's LLC atomics see the 0)
    if (blockIdx.x == 0 && t == 0) *ws_counter = 0u;

    const float4 v = ((const float4*)book)[row * 16 + c4];   // fully coalesced
    float s = v.x * v.x + v.y * v.y + v.z * v.z + v.w * v.w;
    // reduce across the 16 contiguous lanes of this row
    s += __shfl_down(s, 8, 16);
    s += __shfl_down(s, 4, 16);
    s += __shfl_down(s, 2, 16);
    s += __shfl_down(s, 1, 16);

    __shared__ unsigned long long keys[16];
    if (c4 == 0) {
        // positive-float bits are monotone as uint -> u64 min gives min norm,
        // ties broken to LOWEST row (jnp.argmin semantics).
        keys[rIn] = ((unsigned long long)__float_as_uint(s) << 32)
                  | (unsigned int)row;
    }
    __syncthreads();
    if (t == 0) {
        unsigned long long k = keys[0];
        #pragma unroll
        for (int i = 1; i < 16; ++i) k = keys[i] < k ? keys[i] : k;
        ws_keys[blockIdx.x] = k;                  // plain store, no atomic
    }
}

__global__ __launch_bounds__(256) void k2_main(const float* __restrict__ in,
                                               const float* __restrict__ book,
                                               float* __restrict__ out,
                                               const unsigned long long* __restrict__ ws_keys,
                                               float* __restrict__ ws_part,
                                               unsigned int* __restrict__ ws_counter) {
    const int lane = threadIdx.x & 63, wid = threadIdx.x >> 6;
    const int tid  = blockIdx.x * 256 + threadIdx.x;   // 131072 threads

    // ---- prefetch the 4 input float4s NOW: addresses are kmin-independent,
    //      so their HBM latency overlaps wave0's key resolve below ----
    float4 z[K2_ITER];
    #pragma unroll
    for (int it = 0; it < K2_ITER; ++it)
        z[it] = ((const float4*)in)[tid + it * (K2_BLK * 256)];

    // ---- resolve kmin: wave 0 reduces the 512 L2-hot keys, LDS-broadcast ----
    __shared__ unsigned long long skey;
    if (wid == 0) {
        unsigned long long key = ~0ULL;
        #pragma unroll
        for (int j = 0; j < K1_BLK / 64; ++j) {   // 8 strided loads per lane
            unsigned long long o = ws_keys[lane + j * 64];
            key = o < key ? o : key;
        }
        #pragma unroll
        for (int off = 32; off > 0; off >>= 1) {
            unsigned long long o = __shfl_down(key, off, 64);
            key = o < key ? o : key;
        }
        if (lane == 0) skey = key;
    }
    __syncthreads();
    const int kmin = (int)(skey & 0xFFFFFFFFu);
    const float* __restrict__ e = book + kmin * 64;   // L2-hot broadcast

    // ---- idx output: 32768 floats == float(kmin) (blocks 0..31) ----
    if (tid < NIDX / 4) {
        const float kf = (float)kmin;
        ((float4*)(out + NTOT))[tid] = make_float4(kf, kf, kf, kf);
    }

    // ---- z_q out [B,W,C,H] + fused loss over in [B,C,H,W], 4 float4/thread ----
    float part = 0.f;
    #pragma unroll
    for (int it = 0; it < K2_ITER; ++it) {
        const int i = tid + it * (K2_BLK * 256);       // float4 index
        // z_q: float offset o=4i -> value e[(o>>12)&63]
        const float ev = e[(i >> 10) & 63];
        ((float4*)out)[i] = make_float4(ev, ev, ev, ev);
        // loss: in float4 i covers w = (4i&63)..+3
        const float4 zz = z[it];
        const float4 ef = ((const float4*)e)[i & 15];
        const float d0 = zz.x - ef.x, d1 = zz.y - ef.y;
        const float d2 = zz.z - ef.z, d3 = zz.w - ef.w;
        part += d0 * d0 + d1 * d1 + d2 * d2 + d3 * d3;
    }
    #pragma unroll
    for (int off = 32; off > 0; off >>= 1) part += __shfl_down(part, off, 64);

    __shared__ float sp[4];
    __shared__ int   sLast;
    if (lane == 0) sp[wid] = part;
    __syncthreads();
    if (threadIdx.x == 0) {
        const float blkSum = sp[0] + sp[1] + sp[2] + sp[3];
        // relaxed AGENT store -> global_store sc1: write-through to the LLC,
        // no device fence, no L2 flush (the R4 mistake)
        __hip_atomic_store(&ws_part[blockIdx.x], blkSum,
                           __ATOMIC_RELAXED, __HIP_MEMORY_SCOPE_AGENT);
        // drain the sc1 store (and this wave's other vmem) to the LLC before
        // announcing arrival; cheap per-wave stall, no cache operation
        asm volatile("s_waitcnt vmcnt(0)" ::: "memory");
        const unsigned int v = atomicAdd(ws_counter, 1u);  // LLC atomic, det.
        sLast = (v == (unsigned int)(K2_BLK - 1));
    }
    __syncthreads();

    // ---- last block: fold 512 partials (exact k3 summation order) ----
    if (sLast && wid == 0) {
        asm volatile("s_waitcnt vmcnt(0)" ::: "memory");   // order vs atomic
        float s = 0.f;
        #pragma unroll
        for (int j = 0; j < K2_BLK / 64; ++j)
            s += __hip_atomic_load(&ws_part[lane + j * 64],
                                   __ATOMIC_RELAXED, __HIP_MEMORY_SCOPE_AGENT);
        #pragma unroll
        for (int off = 32; off > 0; off >>= 1) s += __shfl_down(s, off, 64);
        if (lane == 0)
            out[NTOT + NIDX] = s * (1.25f / (float)NTOT);
    }
}

extern "C" void kernel_launch(void* const* d_in, const int* in_sizes, int n_in,
                              void* d_out, int out_size, void* d_ws, size_t ws_size,
                              hipStream_t stream) {
    const float* in   = (const float*)d_in[0];   // [8,64,64,64] fp32
    const float* book = (const float*)d_in[1];   // [8192,64] fp32
    float* out = (float*)d_out;

    unsigned long long* ws_keys    = (unsigned long long*)d_ws;
    float*              ws_part    = (float*)((char*)d_ws + 4096);
    unsigned int*       ws_counter = (unsigned int*)((char*)d_ws + 6144);

    k1_argmin<<<K1_BLK, 256, 0, stream>>>(book, ws_keys, ws_counter);
    k2_main<<<K2_BLK, 256, 0, stream>>>(in, book, out, ws_keys, ws_part, ws_counter);
}

// Round 3
// 72.932 us; speedup vs baseline: 1.1447x; 1.0024x over previous
//
#include <hip/hip_runtime.h>

// VQ-VAE codebook forward, B=8,C=64,H=64,W=64, K=8192, D=64.
// Reference quirk: the cross term is a SCALAR, so argmin over k is independent
// of n: idx[n] == argmin_k |book_k|^2 for all n.
// Outputs (concatenated float32):
//   [0 .. 2097151]      z_q permuted to [B,W,C,H]: out[b,w,c,h] = e[w], e=book[kmin]
//   [2097152..2129919]  idx: 32768 x float(kmin)
//   [2129920]           loss = 1.25 * mean((e[w] - in[b,c,h,w])^2)
//
// R6: post-mortem of R4 (+16us, device-fence L2 flushes) and R5 (+5.5us,
// store-drain + 512 same-address LLC atomics): last-block-done fusion is a
// net loss on gfx950 -- dispatch gaps are cheaper than intra-kernel cross-XCD
// sync. Instead, exploit the algebra: sum(e[w]-x)^2 = Sum(x^2)
// - 2*sum_w e_w*S_w + 32768*sum_w e_w^2, where Sum(x^2) and the 64 column
// sums S_w are kmin-INDEPENDENT. So kA = book argmin + in-statistics (all of
// the 8MB in-read moves here, overlapping the book read); kB = pure write
// stream (z_q + idx) + a tiny analytic loss fold by block 0 (133KB of
// partials, coherent via the kernel boundary -- no fences/atomics/counters).
// 3 dispatches -> 2, zero sync tricks, same total HBM traffic.
// Loss is algebraically exact but reassociated (folds in fp64): z_q/idx stay
// bit-exact; loss may differ ~1e-6 from before. If that trips the absmax
// threshold, revert to R3.
// Note: ~43 us of dur_us is the harness's 256 MB d_ws re-poison fill
// (6.2-6.5 TB/s in the profile) -- outside our control.

#define NTOT  2097152   // 8*64*64*64
#define NIDX  32768
#define NBLK  512       // blocks for both kernels

// ws layout: [0    .. 4095]   512 x u64 per-block argmin keys
//            [4096 .. 6143]   512 x f32 per-block sum(x^2) partials
//            [8192 .. 139263] 512 x 16 float4 per-block S_w partials (64 f32 each)

__global__ __launch_bounds__(256) void kA(const float* __restrict__ in,
                                          const float* __restrict__ book,
                                          unsigned long long* __restrict__ ws_keys,
                                          float* __restrict__ ws_sin2,
                                          float4* __restrict__ ws_S) {
    const int t    = threadIdx.x;
    const int b    = blockIdx.x;
    const int lane = t & 63, wid = t >> 6;

    // ---- issue ALL global loads up front (book + in) for latency overlap ----
    const int row = b * 16 + (t >> 4);            // book row, 16 rows/block
    const int c4  = t & 15;                       // float4 column within row
    const float4 bv = ((const float4*)book)[row * 16 + c4];   // coalesced

    float4 z[4];
    #pragma unroll
    for (int it = 0; it < 4; ++it)                // same slice k2 used to read
        z[it] = ((const float4*)in)[b * 256 + t + it * (NBLK * 256)];

    // ---- book |row|^2 argmin (identical to verified R3 k1) ----
    float s = bv.x * bv.x + bv.y * bv.y + bv.z * bv.z + bv.w * bv.w;
    s += __shfl_down(s, 8, 16);
    s += __shfl_down(s, 4, 16);
    s += __shfl_down(s, 2, 16);
    s += __shfl_down(s, 1, 16);

    __shared__ unsigned long long keys[16];
    if (c4 == 0) {
        // positive-float bits are monotone as uint -> u64 min gives min norm,
        // ties broken to LOWEST row (jnp.argmin semantics).
        keys[t >> 4] = ((unsigned long long)__float_as_uint(s) << 32)
                     | (unsigned int)row;
    }

    // ---- in statistics: scalar sum(x^2) and per-w column-sum float4 ----
    // float4 index i = b*256 + t + it*131072; both 256*b and 131072 are
    // multiples of 16, so i mod 16 == t mod 16: this thread ALWAYS covers
    // w = 4*(t&15) .. +3 -> its S-partial is one float4.
    float4 sv = make_float4(0.f, 0.f, 0.f, 0.f);
    float  s2 = 0.f;
    #pragma unroll
    for (int it = 0; it < 4; ++it) {
        sv.x += z[it].x; sv.y += z[it].y; sv.z += z[it].z; sv.w += z[it].w;
        s2 += z[it].x * z[it].x + z[it].y * z[it].y
            + z[it].z * z[it].z + z[it].w * z[it].w;
    }
    // wave-fold sv across lanes sharing (lane&15): lanes l, l+16, l+32, l+48
    sv.x += __shfl_down(sv.x, 32, 64); sv.y += __shfl_down(sv.y, 32, 64);
    sv.z += __shfl_down(sv.z, 32, 64); sv.w += __shfl_down(sv.w, 32, 64);
    sv.x += __shfl_down(sv.x, 16, 64); sv.y += __shfl_down(sv.y, 16, 64);
    sv.z += __shfl_down(sv.z, 16, 64); sv.w += __shfl_down(sv.w, 16, 64);
    // full wave-fold s2
    #pragma unroll
    for (int off = 32; off > 0; off >>= 1) s2 += __shfl_down(s2, off, 64);

    __shared__ float4 sWl[4][16];
    __shared__ float  s2l[4];
    if (lane < 16) sWl[wid][lane] = sv;
    if (lane == 0) s2l[wid] = s2;
    __syncthreads();

    if (t == 0) {
        unsigned long long k = keys[0];
        #pragma unroll
        for (int i = 1; i < 16; ++i) k = keys[i] < k ? keys[i] : k;
        ws_keys[b] = k;                           // plain store, no atomic
    }
    if (t < 16) {
        float4 a = sWl[0][t], b4 = sWl[1][t], c = sWl[2][t], d = sWl[3][t];
        ws_S[b * 16 + t] = make_float4(a.x + b4.x + c.x + d.x,
                                       a.y + b4.y + c.y + d.y,
                                       a.z + b4.z + c.z + d.z,
                                       a.w + b4.w + c.w + d.w);
    }
    if (t == 16)
        ws_sin2[b] = s2l[0] + s2l[1] + s2l[2] + s2l[3];
}

__global__ __launch_bounds__(256) void kB(const float* __restrict__ book,
                                          float* __restrict__ out,
                                          const unsigned long long* __restrict__ ws_keys,
                                          const float* __restrict__ ws_sin2,
                                          const float4* __restrict__ ws_S) {
    const int t    = threadIdx.x;
    const int lane = t & 63, wid = t >> 6;

    // ---- resolve kmin: wave 0 reduces the 512 LLC-hot keys, LDS-broadcast ----
    __shared__ unsigned long long skey;
    if (wid == 0) {
        unsigned long long key = ~0ULL;
        #pragma unroll
        for (int j = 0; j < NBLK / 64; ++j) {     // 8 strided loads per lane
            unsigned long long o = ws_keys[lane + j * 64];
            key = o < key ? o : key;
        }
        #pragma unroll
        for (int off = 32; off > 0; off >>= 1) {
            unsigned long long o = __shfl_down(key, off, 64);
            key = o < key ? o : key;
        }
        if (lane == 0) skey = key;
    }
    __syncthreads();
    const int kmin = (int)(skey & 0xFFFFFFFFu);
    const float* __restrict__ e = book + kmin * 64;   // LLC-hot broadcast

    const int tid = blockIdx.x * 256 + t;             // 131072 threads

    // ---- idx output: 32768 floats == float(kmin) (blocks 0..31) ----
    if (tid < NIDX / 4) {
        const float kf = (float)kmin;
        ((float4*)(out + NTOT))[tid] = make_float4(kf, kf, kf, kf);
    }

    // ---- z_q out [B,W,C,H]: pure broadcast stream, no in-read ----
    #pragma unroll
    for (int it = 0; it < 4; ++it) {
        const int i = tid + it * (NBLK * 256);        // float4 index
        // float offset o=4i -> value e[(o>>12)&63]
        const float ev = e[(i >> 10) & 63];
        ((float4*)out)[i] = make_float4(ev, ev, ev, ev);
    }

    // ---- block 0: analytic loss from kA's partials (133 KB, LLC-hot;
    //      coherent via the kA->kB kernel boundary, no fences needed) ----
    if (blockIdx.x == 0) {
        double a2 = 0.0, aes = 0.0, ae2 = 0.0;
        if (t < 16) {                                 // sum_w e_w^2 (16 float4)
            const float4 ef = ((const float4*)e)[t];
            ae2 = (double)ef.x * ef.x + (double)ef.y * ef.y
                + (double)ef.z * ef.z + (double)ef.w * ef.w;
        }
        #pragma unroll
        for (int h = 0; h < 2; ++h) {                 // thread t: blocks t, t+256
            const int blk = t + h * 256;
            a2 += (double)ws_sin2[blk];
            #pragma unroll
            for (int j = 0; j < 16; ++j) {
                const float4 sv = ws_S[blk * 16 + j];
                const float4 ef = ((const float4*)e)[j];
                aes += (double)sv.x * ef.x + (double)sv.y * ef.y
                     + (double)sv.z * ef.z + (double)sv.w * ef.w;
            }
        }
        #pragma unroll
        for (int off = 32; off > 0; off >>= 1) {
            a2  += __shfl_down(a2,  off, 64);
            aes += __shfl_down(aes, off, 64);
            ae2 += __shfl_down(ae2, off, 64);
        }
        __shared__ double sA[4], sE[4], sQ[4];
        if (lane == 0) { sA[wid] = a2; sE[wid] = aes; sQ[wid] = ae2; }
        __syncthreads();
        if (t == 0) {
            const double A2 = sA[0] + sA[1] + sA[2] + sA[3];
            const double ES = sE[0] + sE[1] + sE[2] + sE[3];
            const double E2 = sQ[0] + sQ[1] + sQ[2] + sQ[3];
            // sum (e[w]-x)^2 = sum x^2 - 2*sum_w e_w S_w + (N/64)*sum_w e_w^2
            const double loss = 1.25 * (A2 - 2.0 * ES + 32768.0 * E2)
                              / (double)NTOT;
            out[NTOT + NIDX] = (float)loss;
        }
    }
}

extern "C" void kernel_launch(void* const* d_in, const int* in_sizes, int n_in,
                              void* d_out, int out_size, void* d_ws, size_t ws_size,
                              hipStream_t stream) {
    const float* in   = (const float*)d_in[0];   // [8,64,64,64] fp32
    const float* book = (const float*)d_in[1];   // [8192,64] fp32
    float* out = (float*)d_out;

    unsigned long long* ws_keys = (unsigned long long*)d_ws;
    float*              ws_sin2 = (float*)((char*)d_ws + 4096);
    float4*             ws_S    = (float4*)((char*)d_ws + 8192);

    kA<<<NBLK, 256, 0, stream>>>(in, book, ws_keys, ws_sin2, ws_S);
    kB<<<NBLK, 256, 0, stream>>>(book, out, ws_keys, ws_sin2, ws_S);
}